// Round 16
// baseline (20450.964 us; speedup 1.0000x reference)
//
#include <hip/hip_runtime.h>
#include <math.h>

#define NB 256
#define NN 256
#define NK 128
#define ND 256
#define NH 512
#define NT 1024

// output layout (floats): x | f_out | u | p_u
#define OUT_X 0
#define OUT_F 65536
#define OUT_U 131072
#define OUT_P 196608

// per-batch ws float offsets
#define EPB   65280            // E levels 1..8 (255*256)
#define SP6O  EPB              // bn6 spec: 4*256
#define S1O   (SP6O + 1024)    // 2*256
#define S2O   (S1O + 512)      // 4*256
#define S3O   (S2O + 1024)     // 8*256
#define LOFFI (S3O + 2048)     // 256 ints (decision-bit slabs)
#define BPB   (LOFFI + 256)

__host__ __device__ __forceinline__ int loff(int d) { return 256 - (1 << (9 - d)); }

// ---------------- G1: LDS-staged weight engine (R14 fixed) ----------------
// W1 streamed via double-buffered 32KB LDS tiles (16 k-rows x 512 cols).
// Staging: LINEAR float4 layout — ((float4*)wbuf)[tid], [tid+1024]:
// consecutive lanes write contiguous 16B -> conflict-free (R14's tid*8
// 32B-stride pattern was a 16-way conflict, 9.5e8 SQ_LDS_BANK_CONFLICT).
// Compute reads wt[k*512+c]: lanes stride-1 floats -> 2 lanes/bank, free.
// MODE: 0 = cn (relu+b1), 1 = bn (+embS[bitR[r]]), 2 = spec (-> rows 2r,2r+1).
template <int R, int MODE>
__device__ void g1lds(const float* __restrict__ A, float* __restrict__ wbuf,
                      float* __restrict__ hid, const int hidBase, const int tid,
                      const float* __restrict__ W1, const float* __restrict__ b1,
                      const float* __restrict__ embS, const int* __restrict__ bitR) {
  constexpr int RPT = (R + 1) / 2;
  const int c = tid & 511;
  const int rg = tid >> 9;
  const int r0 = rg * RPT;
  float acc[RPT];
#pragma unroll
  for (int i = 0; i < RPT; ++i) acc[i] = 0.f;
  // stage tile 0 into buf0 (linear f4)
  {
    const float4* src = (const float4*)W1;
    float4* dst = (float4*)wbuf;
    dst[tid] = src[tid];
    dst[tid + 1024] = src[tid + 1024];
  }
  for (int kt = 0; kt < 32; ++kt) {
    __syncthreads();  // tile kt staged; all waves done reading tile kt-1's buf
    float4 n0 = make_float4(0.f, 0.f, 0.f, 0.f);
    float4 n1 = make_float4(0.f, 0.f, 0.f, 0.f);
    if (kt < 31) {  // issue next-tile loads early; land during compute (T14)
      const float4* src = (const float4*)(W1 + (size_t)(kt + 1) * 8192);
      n0 = src[tid];
      n1 = src[tid + 1024];
    }
    const float* wt = wbuf + (kt & 1) * 8192;
    const int k0 = kt * 16;
#pragma unroll
    for (int kq = 0; kq < 4; ++kq) {
      const float w0 = wt[(kq * 4 + 0) * 512 + c];
      const float w1 = wt[(kq * 4 + 1) * 512 + c];
      const float w2 = wt[(kq * 4 + 2) * 512 + c];
      const float w3 = wt[(kq * 4 + 3) * 512 + c];
#pragma unroll
      for (int i = 0; i < RPT; ++i) {
        const int r = r0 + i;
        if (r < R) {
          const float4 av = *(const float4*)&A[r * 512 + k0 + kq * 4];
          acc[i] += av.x * w0 + av.y * w1 + av.z * w2 + av.w * w3;
        }
      }
    }
    if (kt < 31) {
      float4* dst = (float4*)(wbuf + ((kt + 1) & 1) * 8192);
      dst[tid] = n0;
      dst[tid + 1024] = n1;
    }
  }
#pragma unroll
  for (int i = 0; i < RPT; ++i) {
    const int r = r0 + i;
    if (r < R) {
      const float pre = acc[i] + b1[c];
      if (MODE == 0) {
        hid[(hidBase + r) * 512 + c] = fmaxf(pre, 0.f);
      } else if (MODE == 1) {
        hid[(hidBase + r) * 512 + c] = fmaxf(pre + embS[bitR[r] * 512 + c], 0.f);
      } else {
        hid[(hidBase + 2 * r) * 512 + c] = fmaxf(pre + embS[c], 0.f);
        hid[(hidBase + 2 * r + 1) * 512 + c] = fmaxf(pre + embS[512 + c], 0.f);
      }
    }
  }
  __syncthreads();  // hid ready; wbuf free for reuse as G2 partials
}

// ---------------- G2 engines (R12, proven) ----------------
// g2ks: KS=8 k-eighths x 128 col-pairs; zero redundancy.
template <int RT>
__device__ void g2ks(const float* __restrict__ hid, const int hidBase,
                     float* __restrict__ part, const int tid,
                     const float* __restrict__ W2) {
  const int q = tid >> 7;
  const int c0 = (tid & 127) << 1;
  const float* Wp = W2 + (size_t)(q * 64) * ND + c0;
  const float* Hr = hid + hidBase * 512 + q * 64;
  float a0[RT], a1[RT];
#pragma unroll
  for (int r = 0; r < RT; ++r) { a0[r] = 0.f; a1[r] = 0.f; }
  float2 n0 = *(const float2*)Wp;
  float2 n1 = *(const float2*)(Wp + ND);
  float2 n2 = *(const float2*)(Wp + 2 * ND);
  float2 n3 = *(const float2*)(Wp + 3 * ND);
#pragma unroll 2
  for (int kc = 0; kc < 60; kc += 4) {
    const float2 w0 = n0, w1 = n1, w2 = n2, w3 = n3;
    const float* Wn = Wp + (size_t)(kc + 4) * ND;
    n0 = *(const float2*)Wn;
    n1 = *(const float2*)(Wn + ND);
    n2 = *(const float2*)(Wn + 2 * ND);
    n3 = *(const float2*)(Wn + 3 * ND);
#pragma unroll
    for (int r = 0; r < RT; ++r) {
      const float4 av = *(const float4*)(Hr + r * 512 + kc);
      a0[r] += av.x * w0.x + av.y * w1.x + av.z * w2.x + av.w * w3.x;
      a1[r] += av.x * w0.y + av.y * w1.y + av.z * w2.y + av.w * w3.y;
    }
  }
#pragma unroll
  for (int r = 0; r < RT; ++r) {
    const float4 av = *(const float4*)(Hr + r * 512 + 60);
    a0[r] += av.x * n0.x + av.y * n1.x + av.z * n2.x + av.w * n3.x;
    a1[r] += av.x * n0.y + av.y * n1.y + av.z * n2.y + av.w * n3.y;
  }
#pragma unroll
  for (int r = 0; r < RT; ++r)
    *(float2*)&part[(q * RT + r) * 256 + c0] = make_float2(a0[r], a1[r]);
}

// g2q: KS=16 k-16ths x 64 col-quads (f4 weights).
template <int RT>
__device__ void g2q(const float* __restrict__ hid, const int hidBase,
                    float* __restrict__ part, const int tid,
                    const float* __restrict__ W2) {
  const int q = tid >> 6;
  const int c0 = (tid & 63) << 2;
  const float* Wp = W2 + (size_t)(q * 32) * ND + c0;
  const float* Hr = hid + hidBase * 512 + q * 32;
  float a0[RT], a1[RT], a2[RT], a3[RT];
#pragma unroll
  for (int r = 0; r < RT; ++r) { a0[r] = 0.f; a1[r] = 0.f; a2[r] = 0.f; a3[r] = 0.f; }
  float4 n0 = *(const float4*)Wp;
  float4 n1 = *(const float4*)(Wp + ND);
  float4 n2 = *(const float4*)(Wp + 2 * ND);
  float4 n3 = *(const float4*)(Wp + 3 * ND);
#pragma unroll 2
  for (int kc = 0; kc < 28; kc += 4) {
    const float4 w0 = n0, w1 = n1, w2 = n2, w3 = n3;
    const float* Wn = Wp + (size_t)(kc + 4) * ND;
    n0 = *(const float4*)Wn;
    n1 = *(const float4*)(Wn + ND);
    n2 = *(const float4*)(Wn + 2 * ND);
    n3 = *(const float4*)(Wn + 3 * ND);
#pragma unroll
    for (int r = 0; r < RT; ++r) {
      const float4 av = *(const float4*)(Hr + r * 512 + kc);
      a0[r] += av.x * w0.x + av.y * w1.x + av.z * w2.x + av.w * w3.x;
      a1[r] += av.x * w0.y + av.y * w1.y + av.z * w2.y + av.w * w3.y;
      a2[r] += av.x * w0.z + av.y * w1.z + av.z * w2.z + av.w * w3.z;
      a3[r] += av.x * w0.w + av.y * w1.w + av.z * w2.w + av.w * w3.w;
    }
  }
#pragma unroll
  for (int r = 0; r < RT; ++r) {
    const float4 av = *(const float4*)(Hr + r * 512 + 28);
    a0[r] += av.x * n0.x + av.y * n1.x + av.z * n2.x + av.w * n3.x;
    a1[r] += av.x * n0.y + av.y * n1.y + av.z * n2.y + av.w * n3.y;
    a2[r] += av.x * n0.z + av.y * n1.z + av.z * n2.z + av.w * n3.z;
    a3[r] += av.x * n0.w + av.y * n1.w + av.z * n2.w + av.w * n3.w;
  }
#pragma unroll
  for (int r = 0; r < RT; ++r)
    *(float4*)&part[(q * RT + r) * 256 + c0] = make_float4(a0[r], a1[r], a2[r], a3[r]);
}

template <int KS, int RT>
__device__ void g2red(const float* __restrict__ part, const int tid,
                      const float* __restrict__ b2,
                      float* const* __restrict__ rowDst) {
  for (int i = tid; i < RT * 128; i += NT) {
    const int r = i >> 7, c0 = (i & 127) << 1;
    float2 s = *(const float2*)(b2 + c0);
#pragma unroll
    for (int qq = 0; qq < KS; ++qq) {
      const float2 p = *(const float2*)&part[(qq * RT + r) * 256 + c0];
      s.x += p.x; s.y += p.y;
    }
    *(float2*)(rowDst[r] + c0) = s;
  }
}

__global__ __launch_bounds__(NT, 4) void sc_v16(
    const int* __restrict__ info_bits, const float* __restrict__ rv,
    const int* __restrict__ info_set,
    const float* __restrict__ obs_emb, const float* __restrict__ label_emb,
    const float* __restrict__ cnW1, const float* __restrict__ cnb1,
    const float* __restrict__ cnW2, const float* __restrict__ cnb2,
    const float* __restrict__ bnW1, const float* __restrict__ bnb1,
    const float* __restrict__ bnW2, const float* __restrict__ bnb2,
    const float* __restrict__ llrW, const float* __restrict__ llrb,
    float* __restrict__ out, float* __restrict__ ws) {
  __shared__ float scrU[20480];   // 80KB: G1 W dbuf (16384) / G2 partials (<=20480)
  __shared__ float A[4096];       // <=8 staged input rows (16KB)
  __shared__ float hid[7680];     // 15 hidden rows (30KB)
  __shared__ float embS[1024];    // label_emb[bit] @ bnW1[512:768]
  __shared__ float rowBuf[256];
  __shared__ float* rowDst[16];
  __shared__ int fmap[256];
  __shared__ int curS[256], nxtS[256];
  __shared__ float red[8];
  __shared__ int bitR[8];
  __shared__ int qbS[4];

  const int tid = threadIdx.x, b = blockIdx.x;
  float* wsb = ws + (size_t)b * BPB;
  float* E = wsb;
  float* sp6 = wsb + SP6O;
  float* S1 = wsb + S1O;
  float* S2 = wsb + S2O;
  float* S3 = wsb + S3O;
  int* Lb = (int*)(wsb + LOFFI);
  const float* obs2 = obs_emb + 2 * ND;

  // ---- init: embC + fmap ----
  {
    const int bit = tid >> 9, col = tid & 511;
    float s = 0.f;
#pragma unroll 4
    for (int j = 0; j < ND; ++j)
      s += label_emb[bit * ND + j] * bnW1[(size_t)(NH + j) * NH + col];
    embS[bit * 512 + col] = s;
  }
  if (tid < 256) fmap[tid] = -1;
  __syncthreads();
  if (tid < NK) fmap[info_set[tid]] = tid;
  __syncthreads();

  auto stageA = [&](const float* Ed, int p0, int R) {
    const int n4 = R * 128;
    float4* A4 = (float4*)A;
    if (Ed) {
      const float4* s4 = (const float4*)(Ed + (size_t)(2 * p0) * ND);
      for (int i = tid; i < n4; i += NT) A4[i] = s4[i];
    } else {
      const float4* o4 = (const float4*)obs2;
      for (int i = tid; i < n4; i += NT) A4[i] = o4[i & 63];
    }
  };

  auto plainPass = [&](int d, int isBn) {
    const int P = 1 << (7 - d);
    const float* W1 = isBn ? bnW1 : cnW1;
    const float* B1 = isBn ? bnb1 : cnb1;
    const float* W2 = isBn ? bnW2 : cnW2;
    const float* B2 = isBn ? bnb2 : cnb2;
    const float* Ed = (d == 0) ? nullptr : E + (size_t)loff(d) * ND;
    float* dstE = E + (size_t)loff(d + 1) * ND;
    const int PC = P >= 8 ? 8 : 4;
    for (int p0 = 0; p0 < P; p0 += PC) {
      stageA(Ed, p0, PC);
      if (isBn && tid < PC) bitR[tid] = Lb[loff(d + 1) + p0 + tid];
      if (tid < PC) rowDst[tid] = dstE + (size_t)(p0 + tid) * ND;
      // g1lds's first internal barrier orders these LDS writes.
      if (PC == 8) {
        if (isBn) g1lds<8, 1>(A, scrU, hid, 0, tid, W1, B1, embS, bitR);
        else      g1lds<8, 0>(A, scrU, hid, 0, tid, W1, B1, embS, bitR);
        g2ks<8>(hid, 0, scrU, tid, W2); __syncthreads();
        g2red<8, 8>(scrU, tid, B2, rowDst); __syncthreads();
      } else {
        if (isBn) g1lds<4, 1>(A, scrU, hid, 0, tid, W1, B1, embS, bitR);
        else      g1lds<4, 0>(A, scrU, hid, 0, tid, W1, B1, embS, bitR);
        g2q<4>(hid, 0, scrU, tid, W2); __syncthreads();
        g2red<16, 4>(scrU, tid, B2, rowDst); __syncthreads();
      }
    }
  };

  // uniform initial-descent pass: 1 row + broadcast store (verified R10-R14)
  auto uniPass = [&](int d) {
    const int P = 1 << (7 - d);
    const float* Ed = (d == 0) ? nullptr : E + (size_t)loff(d) * ND;
    float* dstE = E + (size_t)loff(d + 1) * ND;
    stageA(Ed, 0, 1);
    if (tid == 0) rowDst[0] = rowBuf;
    g1lds<1, 0>(A, scrU, hid, 0, tid, cnW1, cnb1, embS, bitR);
    g2q<1>(hid, 0, scrU, tid, cnW2); __syncthreads();
    g2red<16, 1>(scrU, tid, cnb2, rowDst); __syncthreads();
    for (int i = tid; i < P * 256; i += NT) dstE[i] = rowBuf[i & 255];
    __syncthreads();
  };

  // depth-6 pair: cn6 (2 rows -> E7) + bn6 spec (2 rows x 2 bits -> sp6[0..3])
  auto pair6 = [&]() {
    stageA(E + (size_t)loff(6) * ND, 0, 2);
    if (tid < 2) rowDst[tid] = E + (size_t)(252 + tid) * ND;
    g1lds<2, 0>(A, scrU, hid, 0, tid, cnW1, cnb1, embS, bitR);
    g2q<2>(hid, 0, scrU, tid, cnW2); __syncthreads();
    g2red<16, 2>(scrU, tid, cnb2, rowDst); __syncthreads();
    g1lds<2, 2>(A, scrU, hid, 2, tid, bnW1, bnb1, embS, bitR);  // hid[2..6)
    g2ks<4>(hid, 2, scrU, tid, bnW2);
    if (tid < 4) rowDst[tid] = sp6 + (size_t)tid * ND;
    __syncthreads();
    g2red<8, 4>(scrU, tid, bnb2, rowDst); __syncthreads();
  };

  // depth-7 combined: 5 A rows -> cn {E8, S2[0..3]} + bn-spec {S1[0..1], S3[0..7]}
  auto comb = [&]() {
    for (int i = tid; i < 5 * 128; i += NT) {
      const int r = i >> 7, k = (i & 127) << 2;
      const int h = k >> 8;
      const float* src;
      if (r == 0) src = E + (size_t)(252 + h) * ND;
      else {
        const int cc = r - 1;
        const int bit = (h == 0) ? (cc >> 1) : (cc & 1);
        src = sp6 + (size_t)(h * 2 + bit) * ND;
      }
      *(float4*)&A[r * 512 + k] = *(const float4*)&src[k & 255];
    }
    g1lds<5, 0>(A, scrU, hid, 0, tid, cnW1, cnb1, embS, bitR);  // hid[0..5)
    g2ks<5>(hid, 0, scrU, tid, cnW2);
    if (tid < 5) rowDst[tid] = (tid == 0) ? (E + (size_t)254 * ND)
                                          : (S2 + (size_t)(tid - 1) * ND);
    __syncthreads();
    g2red<8, 5>(scrU, tid, cnb2, rowDst); __syncthreads();
    g1lds<5, 2>(A, scrU, hid, 5, tid, bnW1, bnb1, embS, bitR);  // hid[5..15)
    g2ks<10>(hid, 5, scrU, tid, bnW2);
    if (tid < 10) rowDst[tid] = (tid < 2) ? (S1 + (size_t)tid * ND)
                                          : (S3 + (size_t)(tid - 2) * ND);
    __syncthreads();
    g2red<8, 10>(scrU, tid, bnb2, rowDst); __syncthreads();
  };

  auto leaf = [&](int off) {
    const int ph = off & 3;
    const float* src;
    if (ph == 0) src = E + (size_t)254 * ND;
    else if (ph == 1) src = S1 + (size_t)qbS[0] * ND;
    else {
      const int cidx = 2 * (qbS[0] ^ qbS[1]) + qbS[1];
      src = (ph == 2) ? (S2 + (size_t)cidx * ND)
                      : (S3 + (size_t)(2 * cidx + qbS[2]) * ND);
    }
    if (tid < 256) {
      const float ev = src[tid];
      float v0 = ev * llrW[2 * tid];
      float v1 = ev * llrW[2 * tid + 1];
#pragma unroll
      for (int o = 32; o > 0; o >>= 1) {
        v0 += __shfl_down(v0, o);
        v1 += __shfl_down(v1, o);
      }
      if ((tid & 63) == 0) {
        red[tid >> 6] = v0;
        red[4 + (tid >> 6)] = v1;
      }
    }
    __syncthreads();
    if (tid == 0) {
      const float l0 = red[0] + red[1] + red[2] + red[3] + llrb[0];
      const float l1 = red[4] + red[5] + red[6] + red[7] + llrb[1];
      const float m = fmaxf(l0, l1);
      const float e0 = expf(l0 - m), e1 = expf(l1 - m);
      const float s = e0 + e1;
      const float p0 = e0 / s, p1 = e1 / s;
      const int hard = (rv[b * NN + off] > p0) ? 1 : 0;
      const int fidx = fmap[off];
      const int fval = (fidx >= 0) ? info_bits[b * NK + fidx] : 2;
      const int xb = (fval == 2) ? hard : fval;
      out[OUT_F + b * NN + off] = (fidx >= 0) ? 2.0f : (float)xb;
      out[OUT_U + b * NN + off] = (float)xb;
      out[OUT_P + (b * NN + off) * 2 + 0] = p0;
      out[OUT_P + (b * NN + off) * 2 + 1] = p1;
      curS[0] = xb;
      qbS[ph] = xb;
    }
    __syncthreads();
    int* cur = curS;
    int* nxt = nxtS;
    int len = 1, lev = 8, idx = off;
    while (idx & 1) {
      if (tid < len) {
        const int c = cur[tid];
        nxt[2 * tid] = Lb[loff(lev) + tid] ^ c;
        nxt[2 * tid + 1] = c;
      }
      __syncthreads();
      int* t = cur; cur = nxt; nxt = t;
      len <<= 1; idx >>= 1; --lev;
    }
    if (lev > 0) {
      if (tid < len) Lb[loff(lev) + tid] = cur[tid];
    } else {
      if (tid < 256) out[OUT_X + b * NN + tid] = (float)cur[tid];
    }
    __syncthreads();
  };

  // ---- initial descent (uniform rows -> 1-row passes) ----
  for (int d = 0; d <= 5; ++d) uniPass(d);
  pair6();
  comb();

  // ---- leaf loop ----
  for (int off = 0; off < NN; ++off) {
    leaf(off);
    if (off == NN - 1) break;
    const int t = off + 1;
    const int z = __ffs(t) - 1;
    if (z <= 1) continue;  // inside a quad: everything pre-speculated
    const int dbn = 7 - z;  // <= 5
    plainPass(dbn, 1);
    for (int d = dbn + 1; d <= 5; ++d) plainPass(d, 0);
    pair6();
    comb();
  }
}

extern "C" void kernel_launch(void* const* d_in, const int* in_sizes, int n_in,
                              void* d_out, int out_size, void* d_ws, size_t ws_size,
                              hipStream_t stream) {
  const int*   info_bits = (const int*)d_in[0];
  const float* rv        = (const float*)d_in[1];
  const int*   info_set  = (const int*)d_in[2];
  const float* obs_emb   = (const float*)d_in[3];
  const float* label_emb = (const float*)d_in[4];
  const float* cnW1      = (const float*)d_in[5];
  const float* cnb1      = (const float*)d_in[6];
  const float* cnW2      = (const float*)d_in[7];
  const float* cnb2      = (const float*)d_in[8];
  const float* bnW1      = (const float*)d_in[9];
  const float* bnb1      = (const float*)d_in[10];
  const float* bnW2      = (const float*)d_in[11];
  const float* bnb2      = (const float*)d_in[12];
  const float* llrW      = (const float*)d_in[13];
  const float* llrb      = (const float*)d_in[14];

  float* out = (float*)d_out;
  float* ws  = (float*)d_ws;

  sc_v16<<<dim3(NB), dim3(NT), 0, stream>>>(
      info_bits, rv, info_set, obs_emb, label_emb,
      cnW1, cnb1, cnW2, cnb2, bnW1, bnb1, bnW2, bnb2,
      llrW, llrb, out, ws);
}

// Round 17
// 17974.548 us; speedup vs baseline: 1.1378x; 1.1378x over previous
//
#include <hip/hip_runtime.h>
#include <math.h>

#define NB 256
#define NN 256
#define NK 128
#define ND 256
#define NH 512
#define NT 1024

// output layout (floats): x | f_out | u | p_u
#define OUT_X 0
#define OUT_F 65536
#define OUT_U 131072
#define OUT_P 196608

// per-batch ws float offsets
#define EPB   65280            // E levels 1..8 (255*256)
#define SP6O  EPB              // bn6 spec: 4*256
#define S1O   (SP6O + 1024)    // 2*256
#define S2O   (S1O + 512)      // 4*256
#define S3O   (S2O + 1024)     // 8*256
#define LOFFI (S3O + 2048)     // 256 ints (decision-bit slabs)
#define BPB   (LOFFI + 256)

__host__ __device__ __forceinline__ int loff(int d) { return 256 - (1 << (9 - d)); }

// ================= G1 engines: 2-deep ping-pong prefetch =================
// g1ks: KS=4 k-quarters (q=tid>>8) x 256 col-pairs (f2 weights); KN=128.
template <int R>
__device__ void g1ks(const float* __restrict__ Abuf, float* __restrict__ part,
                     const int tid, const float* __restrict__ W1) {
  const int q = tid >> 8;
  const int c0 = (tid & 255) << 1;
  const float* Wp = W1 + (size_t)(q * 128) * NH + c0;
  const float* Ar = Abuf + q * 128;
  float a0[R], a1[R];
#pragma unroll
  for (int r = 0; r < R; ++r) { a0[r] = 0.f; a1[r] = 0.f; }
  float2 P0, P1, P2, P3, Q0, Q1, Q2, Q3;
  auto ldP = [&](int J) {
    const float* w_ = Wp + (size_t)J * NH;
    P0 = *(const float2*)w_;        P1 = *(const float2*)(w_ + NH);
    P2 = *(const float2*)(w_ + 2 * NH); P3 = *(const float2*)(w_ + 3 * NH);
  };
  auto ldQ = [&](int J) {
    const float* w_ = Wp + (size_t)J * NH;
    Q0 = *(const float2*)w_;        Q1 = *(const float2*)(w_ + NH);
    Q2 = *(const float2*)(w_ + 2 * NH); Q3 = *(const float2*)(w_ + 3 * NH);
  };
  auto fmaP = [&](int J) {
#pragma unroll
    for (int r = 0; r < R; ++r) {
      const float4 av = *(const float4*)(Ar + r * 512 + J);
      a0[r] += av.x * P0.x + av.y * P1.x + av.z * P2.x + av.w * P3.x;
      a1[r] += av.x * P0.y + av.y * P1.y + av.z * P2.y + av.w * P3.y;
    }
  };
  auto fmaQ = [&](int J) {
#pragma unroll
    for (int r = 0; r < R; ++r) {
      const float4 av = *(const float4*)(Ar + r * 512 + J);
      a0[r] += av.x * Q0.x + av.y * Q1.x + av.z * Q2.x + av.w * Q3.x;
      a1[r] += av.x * Q0.y + av.y * Q1.y + av.z * Q2.y + av.w * Q3.y;
    }
  };
  ldP(0); ldQ(4);
#pragma unroll 1
  for (int j = 0; j < 112; j += 8) {
    fmaP(j); ldP(j + 8); fmaQ(j + 4); ldQ(j + 12);
  }
  fmaP(112); ldP(120); fmaQ(116); ldQ(124); fmaP(120); fmaQ(124);
#pragma unroll
  for (int r = 0; r < R; ++r)
    *(float2*)&part[(q * R + r) * 512 + c0] = make_float2(a0[r], a1[r]);
}

// g1q: KS=8 k-eighths (q=tid>>7) x 128 col-quads (f4 weights); KN=64.
template <int R>
__device__ void g1q(const float* __restrict__ Abuf, float* __restrict__ part,
                    const int tid, const float* __restrict__ W1) {
  const int q = tid >> 7;
  const int c0 = (tid & 127) << 2;
  const float* Wp = W1 + (size_t)(q * 64) * NH + c0;
  const float* Ar = Abuf + q * 64;
  float a0[R], a1[R], a2[R], a3[R];
#pragma unroll
  for (int r = 0; r < R; ++r) { a0[r] = 0.f; a1[r] = 0.f; a2[r] = 0.f; a3[r] = 0.f; }
  float4 P0, P1, P2, P3, Q0, Q1, Q2, Q3;
  auto ldP = [&](int J) {
    const float* w_ = Wp + (size_t)J * NH;
    P0 = *(const float4*)w_;        P1 = *(const float4*)(w_ + NH);
    P2 = *(const float4*)(w_ + 2 * NH); P3 = *(const float4*)(w_ + 3 * NH);
  };
  auto ldQ = [&](int J) {
    const float* w_ = Wp + (size_t)J * NH;
    Q0 = *(const float4*)w_;        Q1 = *(const float4*)(w_ + NH);
    Q2 = *(const float4*)(w_ + 2 * NH); Q3 = *(const float4*)(w_ + 3 * NH);
  };
  auto fmaP = [&](int J) {
#pragma unroll
    for (int r = 0; r < R; ++r) {
      const float4 av = *(const float4*)(Ar + r * 512 + J);
      a0[r] += av.x * P0.x + av.y * P1.x + av.z * P2.x + av.w * P3.x;
      a1[r] += av.x * P0.y + av.y * P1.y + av.z * P2.y + av.w * P3.y;
      a2[r] += av.x * P0.z + av.y * P1.z + av.z * P2.z + av.w * P3.z;
      a3[r] += av.x * P0.w + av.y * P1.w + av.z * P2.w + av.w * P3.w;
    }
  };
  auto fmaQ = [&](int J) {
#pragma unroll
    for (int r = 0; r < R; ++r) {
      const float4 av = *(const float4*)(Ar + r * 512 + J);
      a0[r] += av.x * Q0.x + av.y * Q1.x + av.z * Q2.x + av.w * Q3.x;
      a1[r] += av.x * Q0.y + av.y * Q1.y + av.z * Q2.y + av.w * Q3.y;
      a2[r] += av.x * Q0.z + av.y * Q1.z + av.z * Q2.z + av.w * Q3.z;
      a3[r] += av.x * Q0.w + av.y * Q1.w + av.z * Q2.w + av.w * Q3.w;
    }
  };
  ldP(0); ldQ(4);
#pragma unroll 1
  for (int j = 0; j < 48; j += 8) {
    fmaP(j); ldP(j + 8); fmaQ(j + 4); ldQ(j + 12);
  }
  fmaP(48); ldP(56); fmaQ(52); ldQ(60); fmaP(56); fmaQ(60);
#pragma unroll
  for (int r = 0; r < R; ++r)
    *(float4*)&part[(q * R + r) * 512 + c0] = make_float4(a0[r], a1[r], a2[r], a3[r]);
}

// ================= G2 engines: 2-deep ping-pong prefetch =================
// g2ks: KS=8 k-eighths x 128 col-pairs (f2 weights); KN=64.
template <int RT>
__device__ void g2ks(const float* __restrict__ hid, const int hidBase,
                     float* __restrict__ part, const int tid,
                     const float* __restrict__ W2) {
  const int q = tid >> 7;
  const int c0 = (tid & 127) << 1;
  const float* Wp = W2 + (size_t)(q * 64) * ND + c0;
  const float* Hr = hid + hidBase * 512 + q * 64;
  float a0[RT], a1[RT];
#pragma unroll
  for (int r = 0; r < RT; ++r) { a0[r] = 0.f; a1[r] = 0.f; }
  float2 P0, P1, P2, P3, Q0, Q1, Q2, Q3;
  auto ldP = [&](int J) {
    const float* w_ = Wp + (size_t)J * ND;
    P0 = *(const float2*)w_;        P1 = *(const float2*)(w_ + ND);
    P2 = *(const float2*)(w_ + 2 * ND); P3 = *(const float2*)(w_ + 3 * ND);
  };
  auto ldQ = [&](int J) {
    const float* w_ = Wp + (size_t)J * ND;
    Q0 = *(const float2*)w_;        Q1 = *(const float2*)(w_ + ND);
    Q2 = *(const float2*)(w_ + 2 * ND); Q3 = *(const float2*)(w_ + 3 * ND);
  };
  auto fmaP = [&](int J) {
#pragma unroll
    for (int r = 0; r < RT; ++r) {
      const float4 av = *(const float4*)(Hr + r * 512 + J);
      a0[r] += av.x * P0.x + av.y * P1.x + av.z * P2.x + av.w * P3.x;
      a1[r] += av.x * P0.y + av.y * P1.y + av.z * P2.y + av.w * P3.y;
    }
  };
  auto fmaQ = [&](int J) {
#pragma unroll
    for (int r = 0; r < RT; ++r) {
      const float4 av = *(const float4*)(Hr + r * 512 + J);
      a0[r] += av.x * Q0.x + av.y * Q1.x + av.z * Q2.x + av.w * Q3.x;
      a1[r] += av.x * Q0.y + av.y * Q1.y + av.z * Q2.y + av.w * Q3.y;
    }
  };
  ldP(0); ldQ(4);
#pragma unroll 1
  for (int j = 0; j < 48; j += 8) {
    fmaP(j); ldP(j + 8); fmaQ(j + 4); ldQ(j + 12);
  }
  fmaP(48); ldP(56); fmaQ(52); ldQ(60); fmaP(56); fmaQ(60);
#pragma unroll
  for (int r = 0; r < RT; ++r)
    *(float2*)&part[(q * RT + r) * 256 + c0] = make_float2(a0[r], a1[r]);
}

// g2q: KS=16 k-16ths x 64 col-quads (f4 weights); KN=32.
template <int RT>
__device__ void g2q(const float* __restrict__ hid, const int hidBase,
                    float* __restrict__ part, const int tid,
                    const float* __restrict__ W2) {
  const int q = tid >> 6;
  const int c0 = (tid & 63) << 2;
  const float* Wp = W2 + (size_t)(q * 32) * ND + c0;
  const float* Hr = hid + hidBase * 512 + q * 32;
  float a0[RT], a1[RT], a2[RT], a3[RT];
#pragma unroll
  for (int r = 0; r < RT; ++r) { a0[r] = 0.f; a1[r] = 0.f; a2[r] = 0.f; a3[r] = 0.f; }
  float4 P0, P1, P2, P3, Q0, Q1, Q2, Q3;
  auto ldP = [&](int J) {
    const float* w_ = Wp + (size_t)J * ND;
    P0 = *(const float4*)w_;        P1 = *(const float4*)(w_ + ND);
    P2 = *(const float4*)(w_ + 2 * ND); P3 = *(const float4*)(w_ + 3 * ND);
  };
  auto ldQ = [&](int J) {
    const float* w_ = Wp + (size_t)J * ND;
    Q0 = *(const float4*)w_;        Q1 = *(const float4*)(w_ + ND);
    Q2 = *(const float4*)(w_ + 2 * ND); Q3 = *(const float4*)(w_ + 3 * ND);
  };
  auto fmaP = [&](int J) {
#pragma unroll
    for (int r = 0; r < RT; ++r) {
      const float4 av = *(const float4*)(Hr + r * 512 + J);
      a0[r] += av.x * P0.x + av.y * P1.x + av.z * P2.x + av.w * P3.x;
      a1[r] += av.x * P0.y + av.y * P1.y + av.z * P2.y + av.w * P3.y;
      a2[r] += av.x * P0.z + av.y * P1.z + av.z * P2.z + av.w * P3.z;
      a3[r] += av.x * P0.w + av.y * P1.w + av.z * P2.w + av.w * P3.w;
    }
  };
  auto fmaQ = [&](int J) {
#pragma unroll
    for (int r = 0; r < RT; ++r) {
      const float4 av = *(const float4*)(Hr + r * 512 + J);
      a0[r] += av.x * Q0.x + av.y * Q1.x + av.z * Q2.x + av.w * Q3.x;
      a1[r] += av.x * Q0.y + av.y * Q1.y + av.z * Q2.y + av.w * Q3.y;
      a2[r] += av.x * Q0.z + av.y * Q1.z + av.z * Q2.z + av.w * Q3.z;
      a3[r] += av.x * Q0.w + av.y * Q1.w + av.z * Q2.w + av.w * Q3.w;
    }
  };
  ldP(0); ldQ(4);
#pragma unroll 1
  for (int j = 0; j < 16; j += 8) {
    fmaP(j); ldP(j + 8); fmaQ(j + 4); ldQ(j + 12);
  }
  fmaP(16); ldP(24); fmaQ(20); ldQ(28); fmaP(24); fmaQ(28);
#pragma unroll
  for (int r = 0; r < RT; ++r)
    *(float4*)&part[(q * RT + r) * 256 + c0] = make_float4(a0[r], a1[r], a2[r], a3[r]);
}

// ================= reduce phases (unchanged from R12) ==================
template <int KS, int PC>
__device__ void g1red(const float* __restrict__ part, float* __restrict__ hid,
                      const int tid, const float* __restrict__ b1,
                      const int isBn, const float* __restrict__ embS,
                      const int* __restrict__ bitR) {
  for (int i = tid; i < PC * 256; i += NT) {
    const int r = i >> 8, c0 = (i & 255) << 1;
    float2 s = *(const float2*)(b1 + c0);
#pragma unroll
    for (int qq = 0; qq < KS; ++qq) {
      const float2 p = *(const float2*)&part[(qq * PC + r) * 512 + c0];
      s.x += p.x; s.y += p.y;
    }
    if (isBn) {
      const float2 e = *(const float2*)&embS[bitR[r] * 512 + c0];
      s.x += e.x; s.y += e.y;
    }
    *(float2*)&hid[r * 512 + c0] = make_float2(fmaxf(s.x, 0.f), fmaxf(s.y, 0.f));
  }
}

template <int KS, int R>
__device__ void g1redspec(const float* __restrict__ part, float* __restrict__ hid,
                          const int base, const int tid,
                          const float* __restrict__ b1,
                          const float* __restrict__ embS) {
  for (int i = tid; i < R * 256; i += NT) {
    const int r = i >> 8, c0 = (i & 255) << 1;
    float2 s = *(const float2*)(b1 + c0);
#pragma unroll
    for (int qq = 0; qq < KS; ++qq) {
      const float2 p = *(const float2*)&part[(qq * R + r) * 512 + c0];
      s.x += p.x; s.y += p.y;
    }
    const float2 e0 = *(const float2*)&embS[c0];
    const float2 e1 = *(const float2*)&embS[512 + c0];
    *(float2*)&hid[(base + 2 * r) * 512 + c0] =
        make_float2(fmaxf(s.x + e0.x, 0.f), fmaxf(s.y + e0.y, 0.f));
    *(float2*)&hid[(base + 2 * r + 1) * 512 + c0] =
        make_float2(fmaxf(s.x + e1.x, 0.f), fmaxf(s.y + e1.y, 0.f));
  }
}

template <int KS, int RT>
__device__ void g2red(const float* __restrict__ part, const int tid,
                      const float* __restrict__ b2,
                      float* const* __restrict__ rowDst) {
  for (int i = tid; i < RT * 128; i += NT) {
    const int r = i >> 7, c0 = (i & 127) << 1;
    float2 s = *(const float2*)(b2 + c0);
#pragma unroll
    for (int qq = 0; qq < KS; ++qq) {
      const float2 p = *(const float2*)&part[(qq * RT + r) * 256 + c0];
      s.x += p.x; s.y += p.y;
    }
    *(float2*)(rowDst[r] + c0) = s;
  }
}

__global__ __launch_bounds__(NT, 4) __attribute__((amdgpu_waves_per_eu(4, 4)))
void sc_quad(
    const int* __restrict__ info_bits, const float* __restrict__ rv,
    const int* __restrict__ info_set,
    const float* __restrict__ obs_emb, const float* __restrict__ label_emb,
    const float* __restrict__ cnW1, const float* __restrict__ cnb1,
    const float* __restrict__ cnW2, const float* __restrict__ cnb2,
    const float* __restrict__ bnW1, const float* __restrict__ bnb1,
    const float* __restrict__ bnW2, const float* __restrict__ bnb2,
    const float* __restrict__ llrW, const float* __restrict__ llrb,
    float* __restrict__ out, float* __restrict__ ws) {
  __shared__ float A[4096];       // <=8 staged input rows
  __shared__ float part[20480];   // k-split partials
  __shared__ float hid[8192];     // <=16 hidden rows
  __shared__ float embS[1024];    // label_emb[bit] @ bnW1[512:768]
  __shared__ float rowBuf[256];   // uniform-pass single output row
  __shared__ float* rowDst[16];
  __shared__ int fmap[256];
  __shared__ int curS[256], nxtS[256];
  __shared__ float red[8];
  __shared__ int bitR[8];
  __shared__ int qbS[4];

  const int tid = threadIdx.x, b = blockIdx.x;
  float* wsb = ws + (size_t)b * BPB;
  float* E = wsb;
  float* sp6 = wsb + SP6O;
  float* S1 = wsb + S1O;
  float* S2 = wsb + S2O;
  float* S3 = wsb + S3O;
  int* Lb = (int*)(wsb + LOFFI);
  const float* obs2 = obs_emb + 2 * ND;

  // ---- init: embC + fmap ----
  {
    const int bit = tid >> 9, col = tid & 511;
    float s = 0.f;
#pragma unroll 4
    for (int j = 0; j < ND; ++j)
      s += label_emb[bit * ND + j] * bnW1[(size_t)(NH + j) * NH + col];
    embS[bit * 512 + col] = s;
  }
  if (tid < 256) fmap[tid] = -1;
  __syncthreads();
  if (tid < NK) fmap[info_set[tid]] = tid;
  __syncthreads();

  auto stageA = [&](const float* Ed, int p0, int R) {
    const int n4 = R * 128;
    float4* A4 = (float4*)A;
    if (Ed) {
      const float4* s4 = (const float4*)(Ed + (size_t)(2 * p0) * ND);
      for (int i = tid; i < n4; i += NT) A4[i] = s4[i];
    } else {
      const float4* o4 = (const float4*)obs2;
      for (int i = tid; i < n4; i += NT) A4[i] = o4[i & 63];
    }
  };

  auto plainPass = [&](int d, int isBn) {
    const int P = 1 << (7 - d);
    const float* W1 = isBn ? bnW1 : cnW1;
    const float* B1 = isBn ? bnb1 : cnb1;
    const float* W2 = isBn ? bnW2 : cnW2;
    const float* B2 = isBn ? bnb2 : cnb2;
    const float* Ed = (d == 0) ? nullptr : E + (size_t)loff(d) * ND;
    float* dstE = E + (size_t)loff(d + 1) * ND;
    const int PC = P >= 8 ? 8 : 4;
    for (int p0 = 0; p0 < P; p0 += PC) {
      stageA(Ed, p0, PC);
      if (isBn && tid < PC) bitR[tid] = Lb[loff(d + 1) + p0 + tid];
      if (tid < PC) rowDst[tid] = dstE + (size_t)(p0 + tid) * ND;
      __syncthreads();
      if (PC == 8) {
        g1ks<8>(A, part, tid, W1); __syncthreads();
        g1red<4, 8>(part, hid, tid, B1, isBn, embS, bitR); __syncthreads();
        g2ks<8>(hid, 0, part, tid, W2); __syncthreads();
        g2red<8, 8>(part, tid, B2, rowDst); __syncthreads();
      } else {
        g1q<4>(A, part, tid, W1); __syncthreads();
        g1red<8, 4>(part, hid, tid, B1, isBn, embS, bitR); __syncthreads();
        g2q<4>(hid, 0, part, tid, W2); __syncthreads();
        g2red<16, 4>(part, tid, B2, rowDst); __syncthreads();
      }
    }
  };

  // uniform initial-descent pass (verified R10-R12): 1 row + broadcast store
  auto uniPass = [&](int d) {
    const int P = 1 << (7 - d);
    const float* Ed = (d == 0) ? nullptr : E + (size_t)loff(d) * ND;
    float* dstE = E + (size_t)loff(d + 1) * ND;
    stageA(Ed, 0, 1);
    if (tid == 0) rowDst[0] = rowBuf;
    __syncthreads();
    g1q<1>(A, part, tid, cnW1); __syncthreads();
    g1red<8, 1>(part, hid, tid, cnb1, 0, embS, bitR); __syncthreads();
    g2q<1>(hid, 0, part, tid, cnW2); __syncthreads();
    g2red<16, 1>(part, tid, cnb2, rowDst); __syncthreads();
    for (int i = tid; i < P * 256; i += NT) dstE[i] = rowBuf[i & 255];
    __syncthreads();
  };

  // depth-6 pair: cn6 (2 rows -> E7) + bn6 spec (2 rows x 2 bits -> sp6[0..3])
  auto pair6 = [&]() {
    stageA(E + (size_t)loff(6) * ND, 0, 2);
    if (tid < 2) rowDst[tid] = E + (size_t)(252 + tid) * ND;
    __syncthreads();
    g1q<2>(A, part, tid, cnW1); __syncthreads();
    g1red<8, 2>(part, hid, tid, cnb1, 0, embS, bitR); __syncthreads();
    g2q<2>(hid, 0, part, tid, cnW2); __syncthreads();
    g2red<16, 2>(part, tid, cnb2, rowDst); __syncthreads();
    g1q<2>(A, part, tid, bnW1); __syncthreads();
    g1redspec<8, 2>(part, hid, 2, tid, bnb1, embS); __syncthreads();
    g2q<4>(hid, 2, part, tid, bnW2);
    if (tid < 4) rowDst[tid] = sp6 + (size_t)tid * ND;
    __syncthreads();
    g2red<16, 4>(part, tid, bnb2, rowDst); __syncthreads();
  };

  // depth-7 combined: 5 A rows -> cn {E8, S2[0..3]} + bn-spec {S1[0..1], S3[0..7]}
  auto comb = [&]() {
    for (int i = tid; i < 5 * 128; i += NT) {
      const int r = i >> 7, k = (i & 127) << 2;
      const int h = k >> 8;
      const float* src;
      if (r == 0) src = E + (size_t)(252 + h) * ND;
      else {
        const int cc = r - 1;
        const int bit = (h == 0) ? (cc >> 1) : (cc & 1);
        src = sp6 + (size_t)(h * 2 + bit) * ND;
      }
      *(float4*)&A[r * 512 + k] = *(const float4*)&src[k & 255];
    }
    __syncthreads();
    g1q<5>(A, part, tid, cnW1); __syncthreads();
    g1red<8, 5>(part, hid, tid, cnb1, 0, embS, bitR); __syncthreads();
    g2q<5>(hid, 0, part, tid, cnW2);
    if (tid < 5) rowDst[tid] = (tid == 0) ? (E + (size_t)254 * ND)
                                          : (S2 + (size_t)(tid - 1) * ND);
    __syncthreads();
    g2red<16, 5>(part, tid, cnb2, rowDst); __syncthreads();
    g1q<5>(A, part, tid, bnW1); __syncthreads();
    g1redspec<8, 5>(part, hid, 5, tid, bnb1, embS); __syncthreads();
    g2ks<10>(hid, 5, part, tid, bnW2);
    if (tid < 10) rowDst[tid] = (tid < 2) ? (S1 + (size_t)tid * ND)
                                          : (S3 + (size_t)(tid - 2) * ND);
    __syncthreads();
    g2red<8, 10>(part, tid, bnb2, rowDst); __syncthreads();
  };

  auto leaf = [&](int off) {
    const int ph = off & 3;
    const float* src;
    if (ph == 0) src = E + (size_t)254 * ND;
    else if (ph == 1) src = S1 + (size_t)qbS[0] * ND;
    else {
      const int cidx = 2 * (qbS[0] ^ qbS[1]) + qbS[1];
      src = (ph == 2) ? (S2 + (size_t)cidx * ND)
                      : (S3 + (size_t)(2 * cidx + qbS[2]) * ND);
    }
    if (tid < 256) {
      const float ev = src[tid];
      float v0 = ev * llrW[2 * tid];
      float v1 = ev * llrW[2 * tid + 1];
#pragma unroll
      for (int o = 32; o > 0; o >>= 1) {
        v0 += __shfl_down(v0, o);
        v1 += __shfl_down(v1, o);
      }
      if ((tid & 63) == 0) {
        red[tid >> 6] = v0;
        red[4 + (tid >> 6)] = v1;
      }
    }
    __syncthreads();
    if (tid == 0) {
      const float l0 = red[0] + red[1] + red[2] + red[3] + llrb[0];
      const float l1 = red[4] + red[5] + red[6] + red[7] + llrb[1];
      const float m = fmaxf(l0, l1);
      const float e0 = expf(l0 - m), e1 = expf(l1 - m);
      const float s = e0 + e1;
      const float p0 = e0 / s, p1 = e1 / s;
      const int hard = (rv[b * NN + off] > p0) ? 1 : 0;
      const int fidx = fmap[off];
      const int fval = (fidx >= 0) ? info_bits[b * NK + fidx] : 2;
      const int xb = (fval == 2) ? hard : fval;
      out[OUT_F + b * NN + off] = (fidx >= 0) ? 2.0f : (float)xb;
      out[OUT_U + b * NN + off] = (float)xb;
      out[OUT_P + (b * NN + off) * 2 + 0] = p0;
      out[OUT_P + (b * NN + off) * 2 + 1] = p1;
      curS[0] = xb;
      qbS[ph] = xb;
    }
    __syncthreads();
    int* cur = curS;
    int* nxt = nxtS;
    int len = 1, lev = 8, idx = off;
    while (idx & 1) {
      if (tid < len) {
        const int c = cur[tid];
        nxt[2 * tid] = Lb[loff(lev) + tid] ^ c;
        nxt[2 * tid + 1] = c;
      }
      __syncthreads();
      int* t = cur; cur = nxt; nxt = t;
      len <<= 1; idx >>= 1; --lev;
    }
    if (lev > 0) {
      if (tid < len) Lb[loff(lev) + tid] = cur[tid];
    } else {
      if (tid < 256) out[OUT_X + b * NN + tid] = (float)cur[tid];
    }
    __syncthreads();
  };

  // ---- initial descent (uniform rows -> 1-row passes) ----
  for (int d = 0; d <= 5; ++d) uniPass(d);
  pair6();
  comb();

  // ---- leaf loop ----
  for (int off = 0; off < NN; ++off) {
    leaf(off);
    if (off == NN - 1) break;
    const int t = off + 1;
    const int z = __ffs(t) - 1;
    if (z <= 1) continue;  // inside a quad: everything pre-speculated
    const int dbn = 7 - z;  // <= 5
    plainPass(dbn, 1);
    for (int d = dbn + 1; d <= 5; ++d) plainPass(d, 0);
    pair6();
    comb();
  }
}

extern "C" void kernel_launch(void* const* d_in, const int* in_sizes, int n_in,
                              void* d_out, int out_size, void* d_ws, size_t ws_size,
                              hipStream_t stream) {
  const int*   info_bits = (const int*)d_in[0];
  const float* rv        = (const float*)d_in[1];
  const int*   info_set  = (const int*)d_in[2];
  const float* obs_emb   = (const float*)d_in[3];
  const float* label_emb = (const float*)d_in[4];
  const float* cnW1      = (const float*)d_in[5];
  const float* cnb1      = (const float*)d_in[6];
  const float* cnW2      = (const float*)d_in[7];
  const float* cnb2      = (const float*)d_in[8];
  const float* bnW1      = (const float*)d_in[9];
  const float* bnb1      = (const float*)d_in[10];
  const float* bnW2      = (const float*)d_in[11];
  const float* bnb2      = (const float*)d_in[12];
  const float* llrW      = (const float*)d_in[13];
  const float* llrb      = (const float*)d_in[14];

  float* out = (float*)d_out;
  float* ws  = (float*)d_ws;

  sc_quad<<<dim3(NB), dim3(NT), 0, stream>>>(
      info_bits, rv, info_set, obs_emb, label_emb,
      cnW1, cnb1, cnW2, cnb2, bnW1, bnb1, bnW2, bnb2,
      llrW, llrb, out, ws);
}

// Round 18
// 10809.608 us; speedup vs baseline: 1.8919x; 1.6628x over previous
//
#include <hip/hip_runtime.h>
#include <math.h>

#define NB 256
#define NN 256
#define NK 128
#define ND 256
#define NH 512
#define NT 1024

// output layout (floats): x | f_out | u | p_u
#define OUT_X 0
#define OUT_F 65536
#define OUT_U 131072
#define OUT_P 196608

// per-batch ws float offsets
#define EPB   65280            // E levels 1..8 (255*256)
#define SP6O  EPB              // bn6 spec: 4*256
#define S1O   (SP6O + 1024)    // 2*256
#define S2O   (S1O + 512)      // 4*256
#define S3O   (S2O + 1024)     // 8*256
#define LOFFI (S3O + 2048)     // 256 ints (decision-bit slabs)
#define BPB   (LOFFI + 256)

__host__ __device__ __forceinline__ int loff(int d) { return 256 - (1 << (9 - d)); }

// ================= legacy engines (R9, proven; used for PC=8 / RT=10) =======
template <int PC>
__device__ void g1ks(const float* __restrict__ Abuf, float* __restrict__ part,
                     const int tid, const float* __restrict__ W1) {
  const int q = tid >> 8;
  const int c0 = (tid & 255) << 1;
  const float* Wp = W1 + (size_t)(q * 128) * NH + c0;
  const float* Ar = Abuf + q * 128;
  float a0[PC], a1[PC];
#pragma unroll
  for (int r = 0; r < PC; ++r) { a0[r] = 0.f; a1[r] = 0.f; }
  float2 n0 = *(const float2*)Wp;
  float2 n1 = *(const float2*)(Wp + NH);
  float2 n2 = *(const float2*)(Wp + 2 * NH);
  float2 n3 = *(const float2*)(Wp + 3 * NH);
#pragma unroll 2
  for (int kc = 0; kc < 124; kc += 4) {
    const float2 w0 = n0, w1 = n1, w2 = n2, w3 = n3;
    const float* Wn = Wp + (size_t)(kc + 4) * NH;
    n0 = *(const float2*)Wn;
    n1 = *(const float2*)(Wn + NH);
    n2 = *(const float2*)(Wn + 2 * NH);
    n3 = *(const float2*)(Wn + 3 * NH);
#pragma unroll
    for (int r = 0; r < PC; ++r) {
      const float4 av = *(const float4*)(Ar + r * 512 + kc);
      a0[r] += av.x * w0.x + av.y * w1.x + av.z * w2.x + av.w * w3.x;
      a1[r] += av.x * w0.y + av.y * w1.y + av.z * w2.y + av.w * w3.y;
    }
  }
#pragma unroll
  for (int r = 0; r < PC; ++r) {
    const float4 av = *(const float4*)(Ar + r * 512 + 124);
    a0[r] += av.x * n0.x + av.y * n1.x + av.z * n2.x + av.w * n3.x;
    a1[r] += av.x * n0.y + av.y * n1.y + av.z * n2.y + av.w * n3.y;
  }
#pragma unroll
  for (int r = 0; r < PC; ++r)
    *(float2*)&part[(q * PC + r) * 512 + c0] = make_float2(a0[r], a1[r]);
}

template <int RT>
__device__ void g2ks(const float* __restrict__ hid, const int hidBase,
                     float* __restrict__ part, const int tid,
                     const float* __restrict__ W2) {
  const int q = tid >> 7;
  const int c0 = (tid & 127) << 1;
  const float* Wp = W2 + (size_t)(q * 64) * ND + c0;
  const float* Hr = hid + hidBase * 512 + q * 64;
  float a0[RT], a1[RT];
#pragma unroll
  for (int r = 0; r < RT; ++r) { a0[r] = 0.f; a1[r] = 0.f; }
  float2 n0 = *(const float2*)Wp;
  float2 n1 = *(const float2*)(Wp + ND);
  float2 n2 = *(const float2*)(Wp + 2 * ND);
  float2 n3 = *(const float2*)(Wp + 3 * ND);
#pragma unroll 2
  for (int kc = 0; kc < 60; kc += 4) {
    const float2 w0 = n0, w1 = n1, w2 = n2, w3 = n3;
    const float* Wn = Wp + (size_t)(kc + 4) * ND;
    n0 = *(const float2*)Wn;
    n1 = *(const float2*)(Wn + ND);
    n2 = *(const float2*)(Wn + 2 * ND);
    n3 = *(const float2*)(Wn + 3 * ND);
#pragma unroll
    for (int r = 0; r < RT; ++r) {
      const float4 av = *(const float4*)(Hr + r * 512 + kc);
      a0[r] += av.x * w0.x + av.y * w1.x + av.z * w2.x + av.w * w3.x;
      a1[r] += av.x * w0.y + av.y * w1.y + av.z * w2.y + av.w * w3.y;
    }
  }
#pragma unroll
  for (int r = 0; r < RT; ++r) {
    const float4 av = *(const float4*)(Hr + r * 512 + 60);
    a0[r] += av.x * n0.x + av.y * n1.x + av.z * n2.x + av.w * n3.x;
    a1[r] += av.x * n0.y + av.y * n1.y + av.z * n2.y + av.w * n3.y;
  }
#pragma unroll
  for (int r = 0; r < RT; ++r)
    *(float2*)&part[(q * RT + r) * 256 + c0] = make_float2(a0[r], a1[r]);
}

// ============== new col-quad engines (f4 weights, half the DS reads) ========
// g1q: 8 k-eighths (q=tid>>7) x 128 col-quads; zero weight redundancy.
template <int PC>
__device__ void g1q(const float* __restrict__ Abuf, float* __restrict__ part,
                    const int tid, const float* __restrict__ W1) {
  const int q = tid >> 7;
  const int c0 = (tid & 127) << 2;
  const float* Wp = W1 + (size_t)(q * 64) * NH + c0;
  const float* Ar = Abuf + q * 64;
  float a0[PC], a1[PC], a2[PC], a3[PC];
#pragma unroll
  for (int r = 0; r < PC; ++r) { a0[r] = 0.f; a1[r] = 0.f; a2[r] = 0.f; a3[r] = 0.f; }
  float4 n0 = *(const float4*)Wp;
  float4 n1 = *(const float4*)(Wp + NH);
  float4 n2 = *(const float4*)(Wp + 2 * NH);
  float4 n3 = *(const float4*)(Wp + 3 * NH);
#pragma unroll 2
  for (int kc = 0; kc < 60; kc += 4) {
    const float4 w0 = n0, w1 = n1, w2 = n2, w3 = n3;
    const float* Wn = Wp + (size_t)(kc + 4) * NH;
    n0 = *(const float4*)Wn;
    n1 = *(const float4*)(Wn + NH);
    n2 = *(const float4*)(Wn + 2 * NH);
    n3 = *(const float4*)(Wn + 3 * NH);
#pragma unroll
    for (int r = 0; r < PC; ++r) {
      const float4 av = *(const float4*)(Ar + r * 512 + kc);
      a0[r] += av.x * w0.x + av.y * w1.x + av.z * w2.x + av.w * w3.x;
      a1[r] += av.x * w0.y + av.y * w1.y + av.z * w2.y + av.w * w3.y;
      a2[r] += av.x * w0.z + av.y * w1.z + av.z * w2.z + av.w * w3.z;
      a3[r] += av.x * w0.w + av.y * w1.w + av.z * w2.w + av.w * w3.w;
    }
  }
#pragma unroll
  for (int r = 0; r < PC; ++r) {
    const float4 av = *(const float4*)(Ar + r * 512 + 60);
    a0[r] += av.x * n0.x + av.y * n1.x + av.z * n2.x + av.w * n3.x;
    a1[r] += av.x * n0.y + av.y * n1.y + av.z * n2.y + av.w * n3.y;
    a2[r] += av.x * n0.z + av.y * n1.z + av.z * n2.z + av.w * n3.z;
    a3[r] += av.x * n0.w + av.y * n1.w + av.z * n2.w + av.w * n3.w;
  }
#pragma unroll
  for (int r = 0; r < PC; ++r)
    *(float4*)&part[(q * PC + r) * 512 + c0] = make_float4(a0[r], a1[r], a2[r], a3[r]);
}

// g2q: 16 k-sixteenths (q=tid>>6) x 64 col-quads; zero redundancy. RT<=5.
template <int RT>
__device__ void g2q(const float* __restrict__ hid, const int hidBase,
                    float* __restrict__ part, const int tid,
                    const float* __restrict__ W2) {
  const int q = tid >> 6;
  const int c0 = (tid & 63) << 2;
  const float* Wp = W2 + (size_t)(q * 32) * ND + c0;
  const float* Hr = hid + hidBase * 512 + q * 32;
  float a0[RT], a1[RT], a2[RT], a3[RT];
#pragma unroll
  for (int r = 0; r < RT; ++r) { a0[r] = 0.f; a1[r] = 0.f; a2[r] = 0.f; a3[r] = 0.f; }
  float4 n0 = *(const float4*)Wp;
  float4 n1 = *(const float4*)(Wp + ND);
  float4 n2 = *(const float4*)(Wp + 2 * ND);
  float4 n3 = *(const float4*)(Wp + 3 * ND);
#pragma unroll 2
  for (int kc = 0; kc < 28; kc += 4) {
    const float4 w0 = n0, w1 = n1, w2 = n2, w3 = n3;
    const float* Wn = Wp + (size_t)(kc + 4) * ND;
    n0 = *(const float4*)Wn;
    n1 = *(const float4*)(Wn + ND);
    n2 = *(const float4*)(Wn + 2 * ND);
    n3 = *(const float4*)(Wn + 3 * ND);
#pragma unroll
    for (int r = 0; r < RT; ++r) {
      const float4 av = *(const float4*)(Hr + r * 512 + kc);
      a0[r] += av.x * w0.x + av.y * w1.x + av.z * w2.x + av.w * w3.x;
      a1[r] += av.x * w0.y + av.y * w1.y + av.z * w2.y + av.w * w3.y;
      a2[r] += av.x * w0.z + av.y * w1.z + av.z * w2.z + av.w * w3.z;
      a3[r] += av.x * w0.w + av.y * w1.w + av.z * w2.w + av.w * w3.w;
    }
  }
#pragma unroll
  for (int r = 0; r < RT; ++r) {
    const float4 av = *(const float4*)(Hr + r * 512 + 28);
    a0[r] += av.x * n0.x + av.y * n1.x + av.z * n2.x + av.w * n3.x;
    a1[r] += av.x * n0.y + av.y * n1.y + av.z * n2.y + av.w * n3.y;
    a2[r] += av.x * n0.z + av.y * n1.z + av.z * n2.z + av.w * n3.z;
    a3[r] += av.x * n0.w + av.y * n1.w + av.z * n2.w + av.w * n3.w;
  }
#pragma unroll
  for (int r = 0; r < RT; ++r)
    *(float4*)&part[(q * RT + r) * 256 + c0] = make_float4(a0[r], a1[r], a2[r], a3[r]);
}

// ================= reduce phases (KS-templated) ==============================
template <int KS, int PC>
__device__ void g1red(const float* __restrict__ part, float* __restrict__ hid,
                      const int tid, const float* __restrict__ b1,
                      const int isBn, const float* __restrict__ embS,
                      const int* __restrict__ bitR) {
  for (int i = tid; i < PC * 256; i += NT) {
    const int r = i >> 8, c0 = (i & 255) << 1;
    float2 s = *(const float2*)(b1 + c0);
#pragma unroll
    for (int qq = 0; qq < KS; ++qq) {
      const float2 p = *(const float2*)&part[(qq * PC + r) * 512 + c0];
      s.x += p.x; s.y += p.y;
    }
    if (isBn) {
      const float2 e = *(const float2*)&embS[bitR[r] * 512 + c0];
      s.x += e.x; s.y += e.y;
    }
    *(float2*)&hid[r * 512 + c0] = make_float2(fmaxf(s.x, 0.f), fmaxf(s.y, 0.f));
  }
}

template <int KS, int R>
__device__ void g1redspec(const float* __restrict__ part, float* __restrict__ hid,
                          const int base, const int tid,
                          const float* __restrict__ b1,
                          const float* __restrict__ embS) {
  for (int i = tid; i < R * 256; i += NT) {
    const int r = i >> 8, c0 = (i & 255) << 1;
    float2 s = *(const float2*)(b1 + c0);
#pragma unroll
    for (int qq = 0; qq < KS; ++qq) {
      const float2 p = *(const float2*)&part[(qq * R + r) * 512 + c0];
      s.x += p.x; s.y += p.y;
    }
    const float2 e0 = *(const float2*)&embS[c0];
    const float2 e1 = *(const float2*)&embS[512 + c0];
    *(float2*)&hid[(base + 2 * r) * 512 + c0] =
        make_float2(fmaxf(s.x + e0.x, 0.f), fmaxf(s.y + e0.y, 0.f));
    *(float2*)&hid[(base + 2 * r + 1) * 512 + c0] =
        make_float2(fmaxf(s.x + e1.x, 0.f), fmaxf(s.y + e1.y, 0.f));
  }
}

template <int KS, int RT>
__device__ void g2red(const float* __restrict__ part, const int tid,
                      const float* __restrict__ b2,
                      float* const* __restrict__ rowDst) {
  for (int i = tid; i < RT * 128; i += NT) {
    const int r = i >> 7, c0 = (i & 127) << 1;
    float2 s = *(const float2*)(b2 + c0);
#pragma unroll
    for (int qq = 0; qq < KS; ++qq) {
      const float2 p = *(const float2*)&part[(qq * RT + r) * 256 + c0];
      s.x += p.x; s.y += p.y;
    }
    *(float2*)(rowDst[r] + c0) = s;
  }
}

__global__ __launch_bounds__(NT, 4) void sc_quad(
    const int* __restrict__ info_bits, const float* __restrict__ rv,
    const int* __restrict__ info_set,
    const float* __restrict__ obs_emb, const float* __restrict__ label_emb,
    const float* __restrict__ cnW1, const float* __restrict__ cnb1,
    const float* __restrict__ cnW2, const float* __restrict__ cnb2,
    const float* __restrict__ bnW1, const float* __restrict__ bnb1,
    const float* __restrict__ bnW2, const float* __restrict__ bnb2,
    const float* __restrict__ llrW, const float* __restrict__ llrb,
    float* __restrict__ out, float* __restrict__ ws) {
  __shared__ float A[4096];       // <=8 staged input rows
  __shared__ float part[20480];   // k-split partials
  __shared__ float hid[8192];     // <=16 hidden rows
  __shared__ float embS[1024];    // label_emb[bit] @ bnW1[512:768]
  __shared__ float rowBuf[256];   // uniform-pass single output row
  __shared__ float* rowDst[16];
  __shared__ int fmap[256];
  __shared__ int curS[256], nxtS[256];
  __shared__ float red[8];
  __shared__ int bitR[8];
  __shared__ int qbS[4];

  const int tid = threadIdx.x, b = blockIdx.x;
  float* wsb = ws + (size_t)b * BPB;
  float* E = wsb;
  float* sp6 = wsb + SP6O;
  float* S1 = wsb + S1O;
  float* S2 = wsb + S2O;
  float* S3 = wsb + S3O;
  int* Lb = (int*)(wsb + LOFFI);
  const float* obs2 = obs_emb + 2 * ND;

  // ---- init: embC + fmap ----
  {
    const int bit = tid >> 9, col = tid & 511;
    float s = 0.f;
#pragma unroll 4
    for (int j = 0; j < ND; ++j)
      s += label_emb[bit * ND + j] * bnW1[(size_t)(NH + j) * NH + col];
    embS[bit * 512 + col] = s;
  }
  if (tid < 256) fmap[tid] = -1;
  __syncthreads();
  if (tid < NK) fmap[info_set[tid]] = tid;
  __syncthreads();

  auto stageA = [&](const float* Ed, int p0, int R) {
    const int n4 = R * 128;
    float4* A4 = (float4*)A;
    if (Ed) {
      const float4* s4 = (const float4*)(Ed + (size_t)(2 * p0) * ND);
      for (int i = tid; i < n4; i += NT) A4[i] = s4[i];
    } else {
      const float4* o4 = (const float4*)obs2;
      for (int i = tid; i < n4; i += NT) A4[i] = o4[i & 63];
    }
  };

  auto plainPass = [&](int d, int isBn) {
    const int P = 1 << (7 - d);
    const float* W1 = isBn ? bnW1 : cnW1;
    const float* B1 = isBn ? bnb1 : cnb1;
    const float* W2 = isBn ? bnW2 : cnW2;
    const float* B2 = isBn ? bnb2 : cnb2;
    const float* Ed = (d == 0) ? nullptr : E + (size_t)loff(d) * ND;
    float* dstE = E + (size_t)loff(d + 1) * ND;
    const int PC = P >= 8 ? 8 : 4;
    for (int p0 = 0; p0 < P; p0 += PC) {
      stageA(Ed, p0, PC);
      if (isBn && tid < PC) bitR[tid] = Lb[loff(d + 1) + p0 + tid];
      if (tid < PC) rowDst[tid] = dstE + (size_t)(p0 + tid) * ND;
      __syncthreads();
      if (PC == 8) {
        g1ks<8>(A, part, tid, W1); __syncthreads();
        g1red<4, 8>(part, hid, tid, B1, isBn, embS, bitR); __syncthreads();
        g2ks<8>(hid, 0, part, tid, W2); __syncthreads();
        g2red<8, 8>(part, tid, B2, rowDst); __syncthreads();
      } else {
        g1q<4>(A, part, tid, W1); __syncthreads();
        g1red<8, 4>(part, hid, tid, B1, isBn, embS, bitR); __syncthreads();
        g2q<4>(hid, 0, part, tid, W2); __syncthreads();
        g2red<16, 4>(part, tid, B2, rowDst); __syncthreads();
      }
    }
  };

  // uniform initial-descent pass (verified R10/R11): 1 row + broadcast store
  auto uniPass = [&](int d) {
    const int P = 1 << (7 - d);
    const float* Ed = (d == 0) ? nullptr : E + (size_t)loff(d) * ND;
    float* dstE = E + (size_t)loff(d + 1) * ND;
    stageA(Ed, 0, 1);
    if (tid == 0) rowDst[0] = rowBuf;
    __syncthreads();
    g1q<1>(A, part, tid, cnW1); __syncthreads();
    g1red<8, 1>(part, hid, tid, cnb1, 0, embS, bitR); __syncthreads();
    g2q<1>(hid, 0, part, tid, cnW2); __syncthreads();
    g2red<16, 1>(part, tid, cnb2, rowDst); __syncthreads();
    for (int i = tid; i < P * 256; i += NT) dstE[i] = rowBuf[i & 255];
    __syncthreads();
  };

  // depth-6 pair: cn6 (2 rows -> E7) + bn6 spec (2 rows x 2 bits -> sp6[0..3])
  auto pair6 = [&]() {
    stageA(E + (size_t)loff(6) * ND, 0, 2);
    if (tid < 2) rowDst[tid] = E + (size_t)(252 + tid) * ND;
    __syncthreads();
    g1q<2>(A, part, tid, cnW1); __syncthreads();
    g1red<8, 2>(part, hid, tid, cnb1, 0, embS, bitR); __syncthreads();
    g2q<2>(hid, 0, part, tid, cnW2); __syncthreads();
    g2red<16, 2>(part, tid, cnb2, rowDst); __syncthreads();
    g1q<2>(A, part, tid, bnW1); __syncthreads();
    g1redspec<8, 2>(part, hid, 2, tid, bnb1, embS); __syncthreads();
    g2q<4>(hid, 2, part, tid, bnW2);
    if (tid < 4) rowDst[tid] = sp6 + (size_t)tid * ND;
    __syncthreads();
    g2red<16, 4>(part, tid, bnb2, rowDst); __syncthreads();
  };

  // depth-7 combined: 5 A rows -> cn {E8, S2[0..3]} + bn-spec {S1[0..1], S3[0..7]}
  auto comb = [&]() {
    for (int i = tid; i < 5 * 128; i += NT) {
      const int r = i >> 7, k = (i & 127) << 2;
      const int h = k >> 8;
      const float* src;
      if (r == 0) src = E + (size_t)(252 + h) * ND;
      else {
        const int cc = r - 1;
        const int bit = (h == 0) ? (cc >> 1) : (cc & 1);
        src = sp6 + (size_t)(h * 2 + bit) * ND;
      }
      *(float4*)&A[r * 512 + k] = *(const float4*)&src[k & 255];
    }
    __syncthreads();
    g1q<5>(A, part, tid, cnW1); __syncthreads();
    g1red<8, 5>(part, hid, tid, cnb1, 0, embS, bitR); __syncthreads();
    g2q<5>(hid, 0, part, tid, cnW2);
    if (tid < 5) rowDst[tid] = (tid == 0) ? (E + (size_t)254 * ND)
                                          : (S2 + (size_t)(tid - 1) * ND);
    __syncthreads();
    g2red<16, 5>(part, tid, cnb2, rowDst); __syncthreads();
    g1q<5>(A, part, tid, bnW1); __syncthreads();
    g1redspec<8, 5>(part, hid, 5, tid, bnb1, embS); __syncthreads();
    g2ks<10>(hid, 5, part, tid, bnW2);
    if (tid < 10) rowDst[tid] = (tid < 2) ? (S1 + (size_t)tid * ND)
                                          : (S3 + (size_t)(tid - 2) * ND);
    __syncthreads();
    g2red<8, 10>(part, tid, bnb2, rowDst); __syncthreads();
  };

  auto leaf = [&](int off) {
    const int ph = off & 3;
    const float* src;
    if (ph == 0) src = E + (size_t)254 * ND;
    else if (ph == 1) src = S1 + (size_t)qbS[0] * ND;
    else {
      const int cidx = 2 * (qbS[0] ^ qbS[1]) + qbS[1];
      src = (ph == 2) ? (S2 + (size_t)cidx * ND)
                      : (S3 + (size_t)(2 * cidx + qbS[2]) * ND);
    }
    if (tid < 256) {
      const float ev = src[tid];
      float v0 = ev * llrW[2 * tid];
      float v1 = ev * llrW[2 * tid + 1];
#pragma unroll
      for (int o = 32; o > 0; o >>= 1) {
        v0 += __shfl_down(v0, o);
        v1 += __shfl_down(v1, o);
      }
      if ((tid & 63) == 0) {
        red[tid >> 6] = v0;
        red[4 + (tid >> 6)] = v1;
      }
    }
    __syncthreads();
    if (tid == 0) {
      const float l0 = red[0] + red[1] + red[2] + red[3] + llrb[0];
      const float l1 = red[4] + red[5] + red[6] + red[7] + llrb[1];
      const float m = fmaxf(l0, l1);
      const float e0 = expf(l0 - m), e1 = expf(l1 - m);
      const float s = e0 + e1;
      const float p0 = e0 / s, p1 = e1 / s;
      const int hard = (rv[b * NN + off] > p0) ? 1 : 0;
      const int fidx = fmap[off];
      const int fval = (fidx >= 0) ? info_bits[b * NK + fidx] : 2;
      const int xb = (fval == 2) ? hard : fval;
      out[OUT_F + b * NN + off] = (fidx >= 0) ? 2.0f : (float)xb;
      out[OUT_U + b * NN + off] = (float)xb;
      out[OUT_P + (b * NN + off) * 2 + 0] = p0;
      out[OUT_P + (b * NN + off) * 2 + 1] = p1;
      curS[0] = xb;
      qbS[ph] = xb;
    }
    __syncthreads();
    int* cur = curS;
    int* nxt = nxtS;
    int len = 1, lev = 8, idx = off;
    while (idx & 1) {
      if (tid < len) {
        const int c = cur[tid];
        nxt[2 * tid] = Lb[loff(lev) + tid] ^ c;
        nxt[2 * tid + 1] = c;
      }
      __syncthreads();
      int* t = cur; cur = nxt; nxt = t;
      len <<= 1; idx >>= 1; --lev;
    }
    if (lev > 0) {
      if (tid < len) Lb[loff(lev) + tid] = cur[tid];
    } else {
      if (tid < 256) out[OUT_X + b * NN + tid] = (float)cur[tid];
    }
    __syncthreads();
  };

  // ---- initial descent (uniform rows -> 1-row passes) ----
  for (int d = 0; d <= 5; ++d) uniPass(d);
  pair6();
  comb();

  // ---- leaf loop ----
  for (int off = 0; off < NN; ++off) {
    leaf(off);
    if (off == NN - 1) break;
    const int t = off + 1;
    const int z = __ffs(t) - 1;
    if (z <= 1) continue;  // inside a quad: everything pre-speculated
    const int dbn = 7 - z;  // <= 5
    plainPass(dbn, 1);
    for (int d = dbn + 1; d <= 5; ++d) plainPass(d, 0);
    pair6();
    comb();
  }
}

extern "C" void kernel_launch(void* const* d_in, const int* in_sizes, int n_in,
                              void* d_out, int out_size, void* d_ws, size_t ws_size,
                              hipStream_t stream) {
  const int*   info_bits = (const int*)d_in[0];
  const float* rv        = (const float*)d_in[1];
  const int*   info_set  = (const int*)d_in[2];
  const float* obs_emb   = (const float*)d_in[3];
  const float* label_emb = (const float*)d_in[4];
  const float* cnW1      = (const float*)d_in[5];
  const float* cnb1      = (const float*)d_in[6];
  const float* cnW2      = (const float*)d_in[7];
  const float* cnb2      = (const float*)d_in[8];
  const float* bnW1      = (const float*)d_in[9];
  const float* bnb1      = (const float*)d_in[10];
  const float* bnW2      = (const float*)d_in[11];
  const float* bnb2      = (const float*)d_in[12];
  const float* llrW      = (const float*)d_in[13];
  const float* llrb      = (const float*)d_in[14];

  float* out = (float*)d_out;
  float* ws  = (float*)d_ws;

  sc_quad<<<dim3(NB), dim3(NT), 0, stream>>>(
      info_bits, rv, info_set, obs_emb, label_emb,
      cnW1, cnb1, cnW2, cnb2, bnW1, bnb1, bnW2, bnb2,
      llrW, llrb, out, ws);
}